// Round 2
// baseline (133.025 us; speedup 1.0000x reference)
//
#include <hip/hip_runtime.h>

// Problem constants (from reference)
#define B_ 32
#define C_ 32
#define T_ 8192
#define N_ 256
#define P_ 6
#define TV_ (T_ - P_ + 1)   // valid conv length = 8187
#define GN 8                // n-values per k_final block

// ---------------------------------------------------------------------------
// k_prep: blocks 0..255 decode one-hot -> chars[B][T] (u8 packed in u32);
//         block 256 discretizes patterns into canonical match tables:
//   xsplat[p][n]: XOR value (req*0x01010101 if unique argmax; 0x7F7F7F7F if
//                 tie (>=2 argmax -> can never match since cnt<=1<psum contrib))
//   orm[p][n]:    0x80808080 if position active, 0 if don't-care (empty col,
//                 only when column sum <= 0 -> contributes 0 to psum and cnt)
// Match(b,t,n) = AND_p [ don't-care OR chars[t+p]==req[p][n] ], pad region
// (t >= TV_) matches iff ALL p are don't-care (psum==0).
// ---------------------------------------------------------------------------
__global__ void k_prep(const float* __restrict__ inp,
                       const float* __restrict__ pat,
                       unsigned* __restrict__ chars32,
                       unsigned* __restrict__ xsplat,
                       unsigned* __restrict__ orm) {
    int bx = blockIdx.x;
    if (bx < B_ * (T_ / 1024)) {
        // ---- one-hot decode: chars[b][t] = sum_c c * input[b,c,t] ----
        int b = bx >> 3;
        int t = ((bx & 7) << 10) + (threadIdx.x << 2);
        const float* base = inp + (size_t)b * C_ * T_ + t;
        float ax = 0.f, ay = 0.f, az = 0.f, aw = 0.f;
        #pragma unroll
        for (int c = 0; c < C_; ++c) {
            float4 v = *(const float4*)(base + (size_t)c * T_);
            float fc = (float)c;
            ax += fc * v.x; ay += fc * v.y; az += fc * v.z; aw += fc * v.w;
        }
        unsigned w = ((unsigned)(ax + 0.5f))
                   | ((unsigned)(ay + 0.5f) << 8)
                   | ((unsigned)(az + 0.5f) << 16)
                   | ((unsigned)(aw + 0.5f) << 24);
        chars32[((size_t)b * T_ + t) >> 2] = w;
    } else {
        // ---- pattern discretization -> canonical tables ----
        for (int i = threadIdx.x; i < P_ * N_; i += 256) {
            int p = i / N_;
            int n = i - p * N_;
            float maxv = -3.402823466e+38f;
            float sum = 0.0f;
            unsigned mask = 0u;
            #pragma unroll
            for (int c = 0; c < C_; ++c) {
                float v = pat[((size_t)c * P_ + p) * N_ + n];
                sum += v;
                if (v > maxv) { maxv = v; mask = (1u << c); }
                else if (v == maxv) { mask |= (1u << c); }
            }
            if (!(sum > 0.0f)) mask = 0u;
            int pc = __popc(mask);
            unsigned xs, om;
            if (pc == 0) {          // column all-zero: don't-care
                xs = 0u;            om = 0u;
            } else if (pc == 1) {   // unique argmax char
                unsigned r = (unsigned)__builtin_ctz(mask);
                xs = r * 0x01010101u;  om = 0x80808080u;
            } else {                // tie: psum contribution >=2 > cnt -> never
                xs = 0x7F7F7F7Fu;   om = 0x80808080u;
            }
            xsplat[i] = xs;
            orm[i]    = om;
        }
    }
}

// ---------------------------------------------------------------------------
// k_final: block = (t-chunk of 1024, group of 8 n, b), 256 threads.
// Each thread: 4 consecutive t for 8 n -> 8 float4 stores.
// Byte-SIMD: x = chars4 ^ xsplat; byte==0 test via (x + 0x7F7F7F7F) bit7
// (exact: all bytes < 0x80, no inter-byte carry). orv bit(8j+7) set iff
// some active p mismatched at t+j.
// ---------------------------------------------------------------------------
__global__ void __launch_bounds__(256)
k_final(const unsigned* __restrict__ chars32,
        const unsigned* __restrict__ xsplat,
        const unsigned* __restrict__ orm,
        float* __restrict__ out) {
    int tc  = blockIdx.x;                 // 0..7
    int ng  = blockIdx.y;                 // 0..31
    int b   = blockIdx.z;                 // 0..31
    int tid = threadIdx.x;
    int t0  = tc << 10;
    int tb  = t0 + (tid << 2);

    // chars words covering t..t+8; OOB halo (end of row / buffer) only
    // pollutes the pad region t >= TV_, which is overwritten below.
    const unsigned* csrc = chars32 + (((size_t)b * T_ + t0) >> 2);
    unsigned w0 = csrc[tid];
    unsigned w1 = csrc[tid + 1];
    unsigned w2 = csrc[tid + 2];
    unsigned cw[P_];
    cw[0] = w0;
    cw[1] = __builtin_amdgcn_alignbyte(w1, w0, 1);
    cw[2] = __builtin_amdgcn_alignbyte(w1, w0, 2);
    cw[3] = __builtin_amdgcn_alignbyte(w1, w0, 3);
    cw[4] = w1;
    cw[5] = __builtin_amdgcn_alignbyte(w2, w1, 1);

    int n0 = ng << 3;
    size_t obase = ((size_t)(b * N_ + n0)) * T_ + tb;

    #pragma unroll
    for (int g = 0; g < GN; ++g) {
        int n = n0 + g;
        unsigned orv = 0u;
        unsigned act = 0u;
        #pragma unroll
        for (int p = 0; p < P_; ++p) {
            unsigned xs = xsplat[p * N_ + n];   // uniform -> s_load
            unsigned om = orm[p * N_ + n];      // uniform -> s_load
            act |= om;
            unsigned x = cw[p] ^ xs;
            orv |= (x + 0x7F7F7F7FU) & om;      // v_and_or_b32
        }
        float padf = (act == 0u) ? 1.0f : 0.0f; // psum==0: pad region matches

        float res[4];
        #pragma unroll
        for (int j = 0; j < 4; ++j) {
            unsigned bad = (orv >> (8 * j + 7)) & 1u;
            res[j] = (float)(bad ^ 1u);
        }
        if (tb + 3 >= TV_) {                    // only last chunk's tail lanes
            #pragma unroll
            for (int j = 0; j < 4; ++j)
                if (tb + j >= TV_) res[j] = padf;
        }
        float4 r; r.x = res[0]; r.y = res[1]; r.z = res[2]; r.w = res[3];
        *(float4*)(out + obase + (size_t)g * T_) = r;
    }
}

// ---------------------------------------------------------------------------
extern "C" void kernel_launch(void* const* d_in, const int* in_sizes, int n_in,
                              void* d_out, int out_size, void* d_ws, size_t ws_size,
                              hipStream_t stream) {
    const float* input_   = (const float*)d_in[0];   // (B,C,T,1) one-hot fp32
    const float* patterns = (const float*)d_in[1];   // (C,P,1,N) fp32
    float* out = (float*)d_out;                      // (B,N,T,1) fp32

    // ws layout: [0,6144) xsplat; [6144,12288) orm; [16384, 16384+256K) chars
    unsigned* xsplat  = (unsigned*)d_ws;
    unsigned* orm     = (unsigned*)d_ws + P_ * N_;
    unsigned* chars32 = (unsigned*)d_ws + 4096;      // byte offset 16384

    hipLaunchKernelGGL(k_prep, dim3(B_ * (T_ / 1024) + 1), dim3(256), 0, stream,
                       input_, patterns, chars32, xsplat, orm);
    hipLaunchKernelGGL(k_final, dim3(T_ / 1024, N_ / GN, B_), dim3(256), 0, stream,
                       chars32, xsplat, orm, out);
}